// Round 1
// baseline (4513.990 us; speedup 1.0000x reference)
//
#include <hip/hip_runtime.h>

#define EMB 384
#define HEADS 6
#define DH 64
#define TT 256

// 384^-0.5
constexpr float SCALE = 0.05103103630798288f;

__global__ __launch_bounds__(256, 1)
void mha_fused(const float* __restrict__ x, const float* __restrict__ Wq,
               const float* __restrict__ Wk, const float* __restrict__ Wv,
               const float* __restrict__ Wp, const float* __restrict__ bp,
               float* __restrict__ out)
{
  const int bh = blockIdx.x;
  const int b = bh / HEADS, h = bh % HEADS;
  const int tid = (int)threadIdx.x;
  const int wave = tid >> 6, lane = tid & 63;

  const float* xb = x + (size_t)b * TT * EMB;
  const float* wq = Wq + (size_t)h * EMB * DH;
  const float* wk = Wk + (size_t)h * EMB * DH;
  const float* wv = Wv + (size_t)h * EMB * DH;

  __shared__ float Ks[TT][68];   // padded: bank = (4s+d)%32, conflict-free-ish
  __shared__ float Vs[TT][64];
  __shared__ float Qt[64][68];

  // ---------------- Phase 1: K, V -> LDS ----------------
  for (int c = 0; c < 4; ++c) {
    const int s0 = wave * 64 + c * 16;
    float ak[16], av[16];
    #pragma unroll
    for (int r = 0; r < 16; ++r) { ak[r] = 0.f; av[r] = 0.f; }
    for (int e = 0; e < EMB; ++e) {
      const float kk = wk[e * DH + lane];
      const float vv = wv[e * DH + lane];
      #pragma unroll
      for (int r = 0; r < 16; ++r) {
        const float xv = xb[(s0 + r) * EMB + e];   // uniform addr -> scalar load
        ak[r] += xv * kk;
        av[r] += xv * vv;
      }
    }
    #pragma unroll
    for (int r = 0; r < 16; ++r) { Ks[s0 + r][lane] = ak[r]; Vs[s0 + r][lane] = av[r]; }
  }
  __syncthreads();

  // cache own K row: thread s = tid owns key/column s
  const int s = tid;
  float kreg[64];
  {
    const float4* k4 = (const float4*)&Ks[s][0];
    #pragma unroll
    for (int i = 0; i < 16; ++i) {
      float4 kv = k4[i];
      kreg[4*i+0] = kv.x; kreg[4*i+1] = kv.y; kreg[4*i+2] = kv.z; kreg[4*i+3] = kv.w;
    }
  }

  // ---------------- Pass A: column sums L_s = sum_{t>=s} exp(scale * q_t . k_s) ----
  float Lsum = 0.f;
  for (int tile = 0; tile < 4; ++tile) {
    { // stage Q rows [tile*64, tile*64+64) into Qt
      const int r0 = tile * 64 + wave * 16;
      float aq[16];
      #pragma unroll
      for (int r = 0; r < 16; ++r) aq[r] = 0.f;
      for (int e = 0; e < EMB; ++e) {
        const float qw = wq[e * DH + lane];
        #pragma unroll
        for (int r = 0; r < 16; ++r) aq[r] += xb[(r0 + r) * EMB + e] * qw;
      }
      __syncthreads();   // previous tile's readers done before overwrite
      #pragma unroll
      for (int r = 0; r < 16; ++r) Qt[wave*16 + r][lane] = aq[r];
      __syncthreads();
    }
    const int tbase = tile * 64;
    if (tbase + 63 >= s) {
      for (int tr = 0; tr < 64; ++tr) {
        const int t = tbase + tr;
        if (t < s) continue;          // causal: only queries t >= s see key s
        float w = 0.f;
        const float4* q4 = (const float4*)&Qt[tr][0];
        #pragma unroll
        for (int i = 0; i < 16; ++i) {
          float4 qv = q4[i];
          w += qv.x*kreg[4*i+0] + qv.y*kreg[4*i+1] + qv.z*kreg[4*i+2] + qv.w*kreg[4*i+3];
        }
        Lsum += __expf(w * SCALE);
      }
    }
  }

  // ---------------- Phase 3: fold 1/L_s into V row s ----------------
  __syncthreads();
  {
    const float invL = 1.0f / Lsum;
    float4* v4 = (float4*)&Vs[s][0];
    #pragma unroll
    for (int i = 0; i < 16; ++i) {
      float4 vv = v4[i];
      vv.x *= invL; vv.y *= invL; vv.z *= invL; vv.w *= invL;
      v4[i] = vv;
    }
  }
  __syncthreads();

  // bias staged once
  const float bias1 = bp[tid];
  const float bias2 = (tid < 128) ? bp[256 + tid] : 0.f;

  // ---------------- Pass B: O = P V', then fused projection ----------------
  const int tr = tid >> 2, dq = tid & 3;   // thread = (query row in tile, d-quarter)
  float* ob = out + (size_t)b * TT * EMB;

  for (int tile = 0; tile < 4; ++tile) {
    { // stage Q tile (recompute)
      const int r0 = tile * 64 + wave * 16;
      float aq[16];
      #pragma unroll
      for (int r = 0; r < 16; ++r) aq[r] = 0.f;
      for (int e = 0; e < EMB; ++e) {
        const float qw = wq[e * DH + lane];
        #pragma unroll
        for (int r = 0; r < 16; ++r) aq[r] += xb[(r0 + r) * EMB + e] * qw;
      }
      __syncthreads();
      #pragma unroll
      for (int r = 0; r < 16; ++r) Qt[wave*16 + r][lane] = aq[r];
      __syncthreads();
    }

    const int t = tile * 64 + tr;
    float qreg[16];
    {
      const float4* q4 = (const float4*)&Qt[tr][dq * 16];
      #pragma unroll
      for (int i = 0; i < 4; ++i) {
        float4 qv = q4[i];
        qreg[4*i+0] = qv.x; qreg[4*i+1] = qv.y; qreg[4*i+2] = qv.z; qreg[4*i+3] = qv.w;
      }
    }
    float acc[16];
    #pragma unroll
    for (int i = 0; i < 16; ++i) acc[i] = 0.f;

    for (int s2 = 0; s2 <= t; ++s2) {
      const float4* kk4 = (const float4*)&Ks[s2][dq * 16];
      float part = 0.f;
      #pragma unroll
      for (int i = 0; i < 4; ++i) {
        float4 kv = kk4[i];
        part += qreg[4*i+0]*kv.x + qreg[4*i+1]*kv.y + qreg[4*i+2]*kv.z + qreg[4*i+3]*kv.w;
      }
      part += __shfl_xor(part, 1);
      part += __shfl_xor(part, 2);      // full 64-dot in all 4 sibling lanes
      const float p = __expf(part * SCALE);
      const float4* vv4 = (const float4*)&Vs[s2][dq * 16];
      #pragma unroll
      for (int i = 0; i < 4; ++i) {
        float4 vv = vv4[i];
        acc[4*i+0] += p * vv.x;
        acc[4*i+1] += p * vv.y;
        acc[4*i+2] += p * vv.z;
        acc[4*i+3] += p * vv.w;
      }
    }

    __syncthreads();                    // everyone done reading Qt (qreg cached)
    #pragma unroll
    for (int i = 0; i < 16; ++i) Qt[tr][dq*16 + i] = acc[i];   // attn tile -> LDS
    __syncthreads();

    // fused projection of this 64-row tile: out[b,t,c] += attn[t, h*64+d] * Wp[h*64+d, c]
    const int c1 = tid;            // cols 0..255
    const int c2 = 256 + tid;      // cols 256..383 (tid < 128)
    for (int rg = 0; rg < 4; ++rg) {
      float a1[16], a2[16];
      #pragma unroll
      for (int r = 0; r < 16; ++r) { a1[r] = 0.f; a2[r] = 0.f; }
      for (int d = 0; d < 64; ++d) {
        const float wp1 = Wp[(size_t)(h*64 + d) * EMB + c1];
        const float wp2 = (tid < 128) ? Wp[(size_t)(h*64 + d) * EMB + c2] : 0.f;
        #pragma unroll
        for (int r = 0; r < 16; ++r) {
          const float a = Qt[rg*16 + r][d];   // broadcast
          a1[r] += a * wp1;
          a2[r] += a * wp2;
        }
      }
      if (h == 0) {
        #pragma unroll
        for (int r = 0; r < 16; ++r) { a1[r] += bias1; a2[r] += bias2; }
      }
      const int trow0 = tile*64 + rg*16;
      #pragma unroll
      for (int r = 0; r < 16; ++r)
        atomicAdd(&ob[(size_t)(trow0 + r) * EMB + c1], a1[r]);
      if (tid < 128) {
        #pragma unroll
        for (int r = 0; r < 16; ++r)
          atomicAdd(&ob[(size_t)(trow0 + r) * EMB + c2], a2[r]);
      }
    }
    __syncthreads();
  }
}

extern "C" void kernel_launch(void* const* d_in, const int* in_sizes, int n_in,
                              void* d_out, int out_size, void* d_ws, size_t ws_size,
                              hipStream_t stream) {
  const float* x  = (const float*)d_in[0];
  const float* Wq = (const float*)d_in[1];
  const float* Wk = (const float*)d_in[2];
  const float* Wv = (const float*)d_in[3];
  const float* Wp = (const float*)d_in[4];
  const float* bp = (const float*)d_in[5];
  float* out = (float*)d_out;

  hipMemsetAsync(out, 0, (size_t)out_size * sizeof(float), stream);
  const int B = in_sizes[0] / (TT * EMB);   // 128
  mha_fused<<<B * HEADS, 256, 0, stream>>>(x, Wq, Wk, Wv, Wp, bp, out);
}

// Round 2
// 157.663 us; speedup vs baseline: 28.6306x; 28.6306x over previous
//
#include <hip/hip_runtime.h>

#define EMB 384
#define HEADS 6
#define DH 64
#define TT 256

constexpr float SCALE = 0.05103103630798288f;  // 384^-0.5

typedef __attribute__((ext_vector_type(8))) short short8;
typedef __attribute__((ext_vector_type(4))) float f32x4;
typedef __attribute__((ext_vector_type(4))) unsigned short u16x4;

__device__ __forceinline__ unsigned short f2bf(float f) {
  unsigned int u = __builtin_bit_cast(unsigned int, f);
  u += 0x7FFFu + ((u >> 16) & 1u);   // RNE
  return (unsigned short)(u >> 16);
}
__device__ __forceinline__ float bf2f(unsigned short u) {
  unsigned int v = ((unsigned int)u) << 16;
  return __builtin_bit_cast(float, v);
}
__device__ __forceinline__ void gll16(const void* g, void* l) {
  __builtin_amdgcn_global_load_lds(
      (const __attribute__((address_space(1))) unsigned int*)g,
      (__attribute__((address_space(3))) unsigned int*)l, 16, 0, 0);
}

// ---------------- K0a: convert x fp32 -> bf16 ----------------
__global__ __launch_bounds__(256)
void cvt_x(const float* __restrict__ x, unsigned short* __restrict__ xb, int n8) {
  int i = blockIdx.x * 256 + threadIdx.x;
  if (i < n8) {
    const float4* src = (const float4*)x;
    float4 a = src[i * 2], b = src[i * 2 + 1];
    short8 o;
    o[0] = (short)f2bf(a.x); o[1] = (short)f2bf(a.y);
    o[2] = (short)f2bf(a.z); o[3] = (short)f2bf(a.w);
    o[4] = (short)f2bf(b.x); o[5] = (short)f2bf(b.y);
    o[6] = (short)f2bf(b.z); o[7] = (short)f2bf(b.w);
    ((short8*)xb)[i] = o;
  }
}

// ---------------- K0b: build Wt[1536][384] bf16 (rows: q 0-383 | k | v | proj^T) ----
__global__ __launch_bounds__(256)
void build_wt(const float* __restrict__ Wq, const float* __restrict__ Wk,
              const float* __restrict__ Wv, const float* __restrict__ Wp,
              unsigned short* __restrict__ Wt) {
  int idx = blockIdx.x * 256 + threadIdx.x;  // 1536*48 = 73728
  int n = idx / 48, e0 = (idx % 48) * 8;
  const float* src; int stride;
  if (n < 1152) {
    int qkv = n / 384, rel = n % 384, h = rel >> 6, d = rel & 63;
    const float* W = (qkv == 0) ? Wq : (qkv == 1) ? Wk : Wv;
    src = W + ((size_t)h * EMB + e0) * DH + d; stride = DH;
  } else {
    int c = n - 1152;
    src = Wp + (size_t)e0 * EMB + c; stride = EMB;
  }
  short8 o;
  #pragma unroll
  for (int j = 0; j < 8; ++j) o[j] = (short)f2bf(src[j * stride]);
  ((short8*)Wt)[idx] = o;
}

// ---------------- unified GEMM: C[M x N] = A[M x 384] * Bt[N x 384]^T ----------------
// MODE 0: QKV epilogue (bf16 stores, V transposed). MODE 1: proj + bias (fp32 out).
template<int MODE>
__global__ __launch_bounds__(256, 2)
void gemm_bt(const unsigned short* __restrict__ A, const unsigned short* __restrict__ Bt,
             unsigned short* __restrict__ Qo, unsigned short* __restrict__ Ko,
             unsigned short* __restrict__ Vto,
             float* __restrict__ Co, const float* __restrict__ bias)
{
  constexpr int Kd = 384;
  __shared__ __align__(16) unsigned short As[2][128 * 64];
  __shared__ __align__(16) unsigned short Bs[2][128 * 64];
  const int tid = threadIdx.x, w = tid >> 6, lane = tid & 63;
  const int m0 = blockIdx.x * 128, n0 = blockIdx.y * 128;
  const int la = lane & 15, kh = lane >> 4;

  auto stage = [&](int buf, int kt) {
    const int k0 = kt * 64;
    #pragma unroll
    for (int i = 0; i < 4; ++i) {
      const int Lb = (w * 4 + i) * 1024;
      const int L = Lb + lane * 16;
      const int row = L >> 7;           // 128B per LDS row (64 bf16)
      const int kcs = ((L >> 4) & 7) ^ (row & 7);  // pre-swizzled source chunk
      gll16(A  + (size_t)(m0 + row) * Kd + k0 + kcs * 8, (char*)As[buf] + Lb);
      gll16(Bt + (size_t)(n0 + row) * Kd + k0 + kcs * 8, (char*)Bs[buf] + Lb);
    }
  };

  f32x4 acc[4][4];
  #pragma unroll
  for (int i = 0; i < 4; ++i)
    #pragma unroll
    for (int j = 0; j < 4; ++j) acc[i][j] = f32x4{0.f, 0.f, 0.f, 0.f};

  const int wr = (w >> 1) * 64, wc = (w & 1) * 64;

  stage(0, 0);
  __syncthreads();
  for (int kt = 0; kt < 6; ++kt) {
    const int buf = kt & 1;
    if (kt + 1 < 6) stage(buf ^ 1, kt + 1);
    #pragma unroll
    for (int kk = 0; kk < 2; ++kk) {
      const int kc = kk * 4 + kh;
      short8 a[4], b[4];
      #pragma unroll
      for (int mi = 0; mi < 4; ++mi) {
        const int r = wr + mi * 16 + la;
        a[mi] = *(const short8*)((const char*)As[buf] + r * 128 + ((kc ^ (r & 7)) << 4));
      }
      #pragma unroll
      for (int ni = 0; ni < 4; ++ni) {
        const int r = wc + ni * 16 + la;
        b[ni] = *(const short8*)((const char*)Bs[buf] + r * 128 + ((kc ^ (r & 7)) << 4));
      }
      #pragma unroll
      for (int mi = 0; mi < 4; ++mi)
        #pragma unroll
        for (int ni = 0; ni < 4; ++ni)
          acc[mi][ni] = __builtin_amdgcn_mfma_f32_16x16x32_bf16(a[mi], b[ni], acc[mi][ni], 0, 0, 0);
    }
    __syncthreads();
  }

  if (MODE == 0) {
    const int qkv = n0 / 384;
    #pragma unroll
    for (int mi = 0; mi < 4; ++mi) {
      const int mbase = m0 + wr + mi * 16 + kh * 4;
      const int bb = mbase >> 8, tt = mbase & 255;
      #pragma unroll
      for (int ni = 0; ni < 4; ++ni) {
        const int nl = n0 + wc + ni * 16 + la;
        const int rel = nl - qkv * 384;
        const int hh = rel >> 6, dd = rel & 63;
        if (qkv == 0) {
          #pragma unroll
          for (int j = 0; j < 4; ++j)
            Qo[(((size_t)bb * 6 + hh) * 256 + (tt + j)) * 64 + dd] = f2bf(acc[mi][ni][j]);
        } else if (qkv == 1) {
          #pragma unroll
          for (int j = 0; j < 4; ++j)
            Ko[(((size_t)bb * 6 + hh) * 256 + (tt + j)) * 64 + dd] = f2bf(acc[mi][ni][j]);
        } else {
          u16x4 pk;
          #pragma unroll
          for (int j = 0; j < 4; ++j) pk[j] = f2bf(acc[mi][ni][j]);
          *(u16x4*)(Vto + (((size_t)bb * 6 + hh) * 64 + dd) * 256 + tt) = pk;  // Vt[b,h,d,t]
        }
      }
    }
  } else {
    #pragma unroll
    for (int mi = 0; mi < 4; ++mi) {
      const int mbase = m0 + wr + mi * 16 + kh * 4;
      #pragma unroll
      for (int ni = 0; ni < 4; ++ni) {
        const int nl = n0 + wc + ni * 16 + la;
        const float bn = bias[nl];
        #pragma unroll
        for (int j = 0; j < 4; ++j)
          Co[(size_t)(mbase + j) * 384 + nl] = acc[mi][ni][j] + bn;
      }
    }
  }
}

// ---------------- K2: attention with per-KEY (axis=2) softmax ----------------
__global__ __launch_bounds__(256, 1)
void attn_col(const unsigned short* __restrict__ Q, const unsigned short* __restrict__ K,
              const unsigned short* __restrict__ Vt, unsigned short* __restrict__ O)
{
  __shared__ __align__(16) char lds[147456];  // QL 32K | KL 32K | EL 80K ; VL overlays QL
  __shared__ float invL[256];
  const int bh = blockIdx.x, tid = threadIdx.x;
  const int w = tid >> 6, lane = tid & 63;
  const int la = lane & 15, kh = lane >> 4;
  const unsigned short* Qg = Q + (size_t)bh * 16384;
  const unsigned short* Kg = K + (size_t)bh * 16384;
  const unsigned short* Vg = Vt + (size_t)bh * 16384;
  char* QL = lds; char* KL = lds + 32768; char* EL = lds + 65536; char* VL = lds;

  // stage Q,K swizzled: LDS [256][64] bf16, content chunk kc holds global chunk kc^(row&7)
  #pragma unroll
  for (int i = 0; i < 8; ++i) {
    const int Lb = (w * 8 + i) * 1024;
    const int L = Lb + lane * 16;
    const int row = L >> 7;
    const int kcs = ((L >> 4) & 7) ^ (row & 7);
    gll16(Qg + row * 64 + kcs * 8, QL + Lb);
    gll16(Kg + row * 64 + kcs * 8, KL + Lb);
  }
  __syncthreads();

  const int Sw = (w + 1) * 64;        // causal col bound for this wave's t-strip
  const int est = 2 * Sw;             // E strip row stride (bytes)
  char* Ew = EL + 8192 * ((w * (w + 1)) >> 1);

  // hoist Q fragments (wave's 64 t-rows)
  short8 qf[4][2];
  #pragma unroll
  for (int mi = 0; mi < 4; ++mi)
    #pragma unroll
    for (int kk = 0; kk < 2; ++kk) {
      const int r = w * 64 + mi * 16 + la;
      const int kc = kk * 4 + kh;
      qf[mi][kk] = *(const short8*)(QL + (r << 7) + ((kc ^ (r & 7)) << 4));
    }

  // S = Q K^T, masked exp -> E strips (bf16, swizzled)
  for (int ns = 0; ns < (w + 1) * 4; ++ns) {
    f32x4 s4[4];
    #pragma unroll
    for (int mi = 0; mi < 4; ++mi) s4[mi] = f32x4{0.f, 0.f, 0.f, 0.f};
    #pragma unroll
    for (int kk = 0; kk < 2; ++kk) {
      const int kc = kk * 4 + kh;
      const int rB = ns * 16 + la;
      short8 bfr = *(const short8*)(KL + (rB << 7) + ((kc ^ (rB & 7)) << 4));
      #pragma unroll
      for (int mi = 0; mi < 4; ++mi)
        s4[mi] = __builtin_amdgcn_mfma_f32_16x16x32_bf16(qf[mi][kk], bfr, s4[mi], 0, 0, 0);
    }
    const int s = ns * 16 + la;
    const int sc = s >> 3, so = (s & 7) << 1;
    #pragma unroll
    for (int mi = 0; mi < 4; ++mi) {
      const int r0 = mi * 16 + kh * 4;
      #pragma unroll
      for (int j = 0; j < 4; ++j) {
        const int r = r0 + j;
        const int t = w * 64 + r;
        const float e = (t >= s) ? __expf(s4[mi][j] * SCALE) : 0.f;
        *(unsigned short*)(Ew + r * est + ((sc ^ (r & 7)) << 4) + so) = f2bf(e);
      }
    }
  }
  __syncthreads();

  // stage Vt[64][256] into VL (overlays QL), swizzled (32 chunks/row)
  #pragma unroll
  for (int i = 0; i < 8; ++i) {
    const int Lb = (w * 8 + i) * 1024;
    const int L = Lb + lane * 16;
    const int row = L >> 9;
    const int kcs = ((L >> 4) & 31) ^ (row & 7);
    gll16(Vg + row * 256 + kcs * 8, VL + Lb);
  }
  // column sums: thread <-> key s; L_s = sum_{t>=s} E[t,s]
  {
    const int s = tid;
    const int sc = s >> 3, so = (s & 7) << 1;
    float Ls = 0.f;
    for (int ww = 0; ww < 4; ++ww) {
      if (s < (ww + 1) * 64) {
        char* E2 = EL + 8192 * ((ww * (ww + 1)) >> 1);
        const int e2 = 128 * (ww + 1);
        float p = 0.f;
        for (int r = 0; r < 64; ++r)
          p += bf2f(*(const unsigned short*)(E2 + r * e2 + ((sc ^ (r & 7)) << 4) + so));
        Ls += p;
      }
    }
    invL[s] = 1.f / Ls;
  }
  __syncthreads();   // drains V staging (vmcnt) + invL visible

  // fold 1/L_s into V rows (VL logical [d][s])
  {
    const int d = tid >> 2, qq = tid & 3;
    #pragma unroll
    for (int c = 0; c < 8; ++c) {
      const int kc = qq * 8 + c;
      char* p = VL + (d << 9) + ((kc ^ (d & 7)) << 4);
      short8 v = *(short8*)p;
      short8 o;
      #pragma unroll
      for (int e = 0; e < 8; ++e)
        o[e] = (short)f2bf(bf2f((unsigned short)v[e]) * invL[kc * 8 + e]);
      *(short8*)p = o;
    }
  }
  __syncthreads();

  // O = E * V' (per wave: own 64-row strip)
  f32x4 oacc[4][4];
  #pragma unroll
  for (int i = 0; i < 4; ++i)
    #pragma unroll
    for (int j = 0; j < 4; ++j) oacc[i][j] = f32x4{0.f, 0.f, 0.f, 0.f};

  for (int ks = 0; ks < (w + 1) * 2; ++ks) {
    const int kc = ks * 4 + kh;
    short8 af[4], bfr[4];
    #pragma unroll
    for (int mi = 0; mi < 4; ++mi) {
      const int r = mi * 16 + la;
      af[mi] = *(const short8*)(Ew + r * est + ((kc ^ (r & 7)) << 4));
    }
    #pragma unroll
    for (int nd = 0; nd < 4; ++nd) {
      const int dc = nd * 16 + la;
      bfr[nd] = *(const short8*)(VL + (dc << 9) + ((kc ^ (dc & 7)) << 4));
    }
    #pragma unroll
    for (int mi = 0; mi < 4; ++mi)
      #pragma unroll
      for (int nd = 0; nd < 4; ++nd)
        oacc[mi][nd] = __builtin_amdgcn_mfma_f32_16x16x32_bf16(af[mi], bfr[nd], oacc[mi][nd], 0, 0, 0);
  }

  const int b = bh / 6, h = bh - b * 6;
  unsigned short* Og = O + (size_t)b * 256 * 384 + h * 64;
  #pragma unroll
  for (int mi = 0; mi < 4; ++mi)
    #pragma unroll
    for (int nd = 0; nd < 4; ++nd) {
      const int d = nd * 16 + la;
      const int t0 = w * 64 + mi * 16 + kh * 4;
      #pragma unroll
      for (int j = 0; j < 4; ++j)
        Og[(size_t)(t0 + j) * 384 + d] = f2bf(oacc[mi][nd][j]);
    }
}

// ================= fallback (round-1 fp32 kernel) for small ws =================
__global__ __launch_bounds__(256, 1)
void mha_fused(const float* __restrict__ x, const float* __restrict__ Wq,
               const float* __restrict__ Wk, const float* __restrict__ Wv,
               const float* __restrict__ Wp, const float* __restrict__ bp,
               float* __restrict__ out)
{
  const int bh = blockIdx.x;
  const int b = bh / HEADS, h = bh % HEADS;
  const int tid = (int)threadIdx.x;
  const int wave = tid >> 6, lane = tid & 63;
  const float* xb = x + (size_t)b * TT * EMB;
  const float* wq = Wq + (size_t)h * EMB * DH;
  const float* wk = Wk + (size_t)h * EMB * DH;
  const float* wv = Wv + (size_t)h * EMB * DH;
  __shared__ float Ks[TT][68];
  __shared__ float Vs[TT][64];
  __shared__ float Qt[64][68];
  for (int c = 0; c < 4; ++c) {
    const int s0 = wave * 64 + c * 16;
    float ak[16], av[16];
    #pragma unroll
    for (int r = 0; r < 16; ++r) { ak[r] = 0.f; av[r] = 0.f; }
    for (int e = 0; e < EMB; ++e) {
      const float kk = wk[e * DH + lane];
      const float vv = wv[e * DH + lane];
      #pragma unroll
      for (int r = 0; r < 16; ++r) {
        const float xv = xb[(s0 + r) * EMB + e];
        ak[r] += xv * kk; av[r] += xv * vv;
      }
    }
    #pragma unroll
    for (int r = 0; r < 16; ++r) { Ks[s0 + r][lane] = ak[r]; Vs[s0 + r][lane] = av[r]; }
  }
  __syncthreads();
  const int s = tid;
  float kreg[64];
  {
    const float4* k4 = (const float4*)&Ks[s][0];
    #pragma unroll
    for (int i = 0; i < 16; ++i) {
      float4 kv = k4[i];
      kreg[4*i+0] = kv.x; kreg[4*i+1] = kv.y; kreg[4*i+2] = kv.z; kreg[4*i+3] = kv.w;
    }
  }
  float Lsum = 0.f;
  for (int tile = 0; tile < 4; ++tile) {
    {
      const int r0 = tile * 64 + wave * 16;
      float aq[16];
      #pragma unroll
      for (int r = 0; r < 16; ++r) aq[r] = 0.f;
      for (int e = 0; e < EMB; ++e) {
        const float qw = wq[e * DH + lane];
        #pragma unroll
        for (int r = 0; r < 16; ++r) aq[r] += xb[(r0 + r) * EMB + e] * qw;
      }
      __syncthreads();
      #pragma unroll
      for (int r = 0; r < 16; ++r) Qt[wave*16 + r][lane] = aq[r];
      __syncthreads();
    }
    const int tbase = tile * 64;
    if (tbase + 63 >= s) {
      for (int tr = 0; tr < 64; ++tr) {
        const int t = tbase + tr;
        if (t < s) continue;
        float w = 0.f;
        const float4* q4 = (const float4*)&Qt[tr][0];
        #pragma unroll
        for (int i = 0; i < 16; ++i) {
          float4 qv = q4[i];
          w += qv.x*kreg[4*i+0] + qv.y*kreg[4*i+1] + qv.z*kreg[4*i+2] + qv.w*kreg[4*i+3];
        }
        Lsum += __expf(w * SCALE);
      }
    }
  }
  __syncthreads();
  {
    const float invL = 1.0f / Lsum;
    float4* v4 = (float4*)&Vs[s][0];
    #pragma unroll
    for (int i = 0; i < 16; ++i) {
      float4 vv = v4[i];
      vv.x *= invL; vv.y *= invL; vv.z *= invL; vv.w *= invL;
      v4[i] = vv;
    }
  }
  __syncthreads();
  const float bias1 = bp[tid];
  const float bias2 = (tid < 128) ? bp[256 + tid] : 0.f;
  const int tr = tid >> 2, dq = tid & 3;
  float* ob = out + (size_t)b * TT * EMB;
  for (int tile = 0; tile < 4; ++tile) {
    {
      const int r0 = tile * 64 + wave * 16;
      float aq[16];
      #pragma unroll
      for (int r = 0; r < 16; ++r) aq[r] = 0.f;
      for (int e = 0; e < EMB; ++e) {
        const float qw = wq[e * DH + lane];
        #pragma unroll
        for (int r = 0; r < 16; ++r) aq[r] += xb[(r0 + r) * EMB + e] * qw;
      }
      __syncthreads();
      #pragma unroll
      for (int r = 0; r < 16; ++r) Qt[wave*16 + r][lane] = aq[r];
      __syncthreads();
    }
    const int t = tile * 64 + tr;
    float qreg[16];
    {
      const float4* q4 = (const float4*)&Qt[tr][dq * 16];
      #pragma unroll
      for (int i = 0; i < 4; ++i) {
        float4 qv = q4[i];
        qreg[4*i+0] = qv.x; qreg[4*i+1] = qv.y; qreg[4*i+2] = qv.z; qreg[4*i+3] = qv.w;
      }
    }
    float acc[16];
    #pragma unroll
    for (int i = 0; i < 16; ++i) acc[i] = 0.f;
    for (int s2 = 0; s2 <= t; ++s2) {
      const float4* kk4 = (const float4*)&Ks[s2][dq * 16];
      float part = 0.f;
      #pragma unroll
      for (int i = 0; i < 4; ++i) {
        float4 kv = kk4[i];
        part += qreg[4*i+0]*kv.x + qreg[4*i+1]*kv.y + qreg[4*i+2]*kv.z + qreg[4*i+3]*kv.w;
      }
      part += __shfl_xor(part, 1);
      part += __shfl_xor(part, 2);
      const float p = __expf(part * SCALE);
      const float4* vv4 = (const float4*)&Vs[s2][dq * 16];
      #pragma unroll
      for (int i = 0; i < 4; ++i) {
        float4 vv = vv4[i];
        acc[4*i+0] += p * vv.x; acc[4*i+1] += p * vv.y;
        acc[4*i+2] += p * vv.z; acc[4*i+3] += p * vv.w;
      }
    }
    __syncthreads();
    #pragma unroll
    for (int i = 0; i < 16; ++i) Qt[tr][dq*16 + i] = acc[i];
    __syncthreads();
    const int c1 = tid;
    const int c2 = 256 + tid;
    for (int rg = 0; rg < 4; ++rg) {
      float a1[16], a2[16];
      #pragma unroll
      for (int r = 0; r < 16; ++r) { a1[r] = 0.f; a2[r] = 0.f; }
      for (int d = 0; d < 64; ++d) {
        const float wp1 = Wp[(size_t)(h*64 + d) * EMB + c1];
        const float wp2 = (tid < 128) ? Wp[(size_t)(h*64 + d) * EMB + c2] : 0.f;
        #pragma unroll
        for (int r = 0; r < 16; ++r) {
          const float a = Qt[rg*16 + r][d];
          a1[r] += a * wp1; a2[r] += a * wp2;
        }
      }
      if (h == 0) {
        #pragma unroll
        for (int r = 0; r < 16; ++r) { a1[r] += bias1; a2[r] += bias2; }
      }
      const int trow0 = tile*64 + rg*16;
      #pragma unroll
      for (int r = 0; r < 16; ++r)
        atomicAdd(&ob[(size_t)(trow0 + r) * EMB + c1], a1[r]);
      if (tid < 128) {
        #pragma unroll
        for (int r = 0; r < 16; ++r)
          atomicAdd(&ob[(size_t)(trow0 + r) * EMB + c2], a2[r]);
      }
    }
    __syncthreads();
  }
}

extern "C" void kernel_launch(void* const* d_in, const int* in_sizes, int n_in,
                              void* d_out, int out_size, void* d_ws, size_t ws_size,
                              hipStream_t stream) {
  const float* x  = (const float*)d_in[0];
  const float* Wq = (const float*)d_in[1];
  const float* Wk = (const float*)d_in[2];
  const float* Wv = (const float*)d_in[3];
  const float* Wp = (const float*)d_in[4];
  const float* bp = (const float*)d_in[5];

  const int nb = in_sizes[0] / (TT * EMB);       // batch (128)
  const size_t M = (size_t)nb * TT;              // 32768 rows
  const size_t XB = M * EMB * 2;                 // bf16 activation bytes (25 MB)

  const size_t off_x  = 0;
  const size_t off_wt = XB;
  const size_t off_q  = off_wt + (size_t)1536 * 384 * 2;
  const size_t off_k  = off_q + XB;
  const size_t off_vt = off_k + XB;
  const size_t off_o  = 0;                       // O overlays xb16 (stream-ordered safe)
  const size_t need   = off_vt + XB;

  if (ws_size < need) {
    hipMemsetAsync(d_out, 0, (size_t)out_size * sizeof(float), stream);
    mha_fused<<<nb * HEADS, 256, 0, stream>>>(x, Wq, Wk, Wv, Wp, bp, (float*)d_out);
    return;
  }

  char* ws = (char*)d_ws;
  unsigned short* xb16 = (unsigned short*)(ws + off_x);
  unsigned short* Wt   = (unsigned short*)(ws + off_wt);
  unsigned short* Qw   = (unsigned short*)(ws + off_q);
  unsigned short* Kw   = (unsigned short*)(ws + off_k);
  unsigned short* Vtw  = (unsigned short*)(ws + off_vt);
  unsigned short* Ow   = (unsigned short*)(ws + off_o);

  const int n8 = (int)(M * EMB / 8);
  cvt_x<<<(n8 + 255) / 256, 256, 0, stream>>>(x, xb16, n8);
  build_wt<<<288, 256, 0, stream>>>(Wq, Wk, Wv, Wp, Wt);

  dim3 g1((unsigned)(M / 128), 9);
  gemm_bt<0><<<g1, 256, 0, stream>>>(xb16, Wt, Qw, Kw, Vtw, nullptr, nullptr);

  attn_col<<<nb * HEADS, 256, 0, stream>>>(Qw, Kw, Vtw, Ow);

  dim3 g3((unsigned)(M / 128), 3);
  gemm_bt<1><<<g3, 256, 0, stream>>>(Ow, Wt + (size_t)1152 * 384, nullptr, nullptr, nullptr,
                                     (float*)d_out, bp);
}

// Round 3
// 141.493 us; speedup vs baseline: 31.9025x; 1.1143x over previous
//
#include <hip/hip_runtime.h>

#define EMB 384
#define HEADS 6
#define DH 64
#define TT 256

constexpr float SCALE = 0.05103103630798288f;  // 384^-0.5

typedef __attribute__((ext_vector_type(8))) short short8;
typedef __attribute__((ext_vector_type(4))) float f32x4;
typedef __attribute__((ext_vector_type(4))) unsigned short u16x4;

__device__ __forceinline__ unsigned short f2bf(float f) {
  unsigned int u = __builtin_bit_cast(unsigned int, f);
  u += 0x7FFFu + ((u >> 16) & 1u);   // RNE
  return (unsigned short)(u >> 16);
}
__device__ __forceinline__ float bf2f(unsigned short u) {
  unsigned int v = ((unsigned int)u) << 16;
  return __builtin_bit_cast(float, v);
}
__device__ __forceinline__ void gll16(const void* g, void* l) {
  __builtin_amdgcn_global_load_lds(
      (const __attribute__((address_space(1))) unsigned int*)g,
      (__attribute__((address_space(3))) unsigned int*)l, 16, 0, 0);
}

// ---------------- K0a: convert x fp32 -> bf16 ----------------
__global__ __launch_bounds__(256)
void cvt_x(const float* __restrict__ x, unsigned short* __restrict__ xb, int n8) {
  int i = blockIdx.x * 256 + threadIdx.x;
  if (i < n8) {
    const float4* src = (const float4*)x;
    float4 a = src[i * 2], b = src[i * 2 + 1];
    short8 o;
    o[0] = (short)f2bf(a.x); o[1] = (short)f2bf(a.y);
    o[2] = (short)f2bf(a.z); o[3] = (short)f2bf(a.w);
    o[4] = (short)f2bf(b.x); o[5] = (short)f2bf(b.y);
    o[6] = (short)f2bf(b.z); o[7] = (short)f2bf(b.w);
    ((short8*)xb)[i] = o;
  }
}

// ---------------- K0b: build Wt[1536][384] bf16 (rows: q 0-383 | k | v | proj^T) ----
__global__ __launch_bounds__(256)
void build_wt(const float* __restrict__ Wq, const float* __restrict__ Wk,
              const float* __restrict__ Wv, const float* __restrict__ Wp,
              unsigned short* __restrict__ Wt) {
  int idx = blockIdx.x * 256 + threadIdx.x;  // 1536*48 = 73728
  int n = idx / 48, e0 = (idx % 48) * 8;
  const float* src; int stride;
  if (n < 1152) {
    int qkv = n / 384, rel = n % 384, h = rel >> 6, d = rel & 63;
    const float* W = (qkv == 0) ? Wq : (qkv == 1) ? Wk : Wv;
    src = W + ((size_t)h * EMB + e0) * DH + d; stride = DH;
  } else {
    int c = n - 1152;
    src = Wp + (size_t)e0 * EMB + c; stride = EMB;
  }
  short8 o;
  #pragma unroll
  for (int j = 0; j < 8; ++j) o[j] = (short)f2bf(src[j * stride]);
  ((short8*)Wt)[idx] = o;
}

// ---------------- unified GEMM: C[M x N] = A[M x 384] * Bt[N x 384]^T ----------------
// grid = (N/128, M/128): consecutive blocks share the A-panel (L2/L3 locality).
template<int MODE>
__global__ __launch_bounds__(256, 2)
void gemm_bt(const unsigned short* __restrict__ A, const unsigned short* __restrict__ Bt,
             unsigned short* __restrict__ Qo, unsigned short* __restrict__ Ko,
             unsigned short* __restrict__ Vto,
             float* __restrict__ Co, const float* __restrict__ bias)
{
  constexpr int Kd = 384;
  __shared__ __align__(16) unsigned short As[2][128 * 64];
  __shared__ __align__(16) unsigned short Bs[2][128 * 64];
  const int tid = threadIdx.x, w = tid >> 6, lane = tid & 63;
  const int m0 = blockIdx.y * 128, n0 = blockIdx.x * 128;
  const int la = lane & 15, kh = lane >> 4;

  auto stage = [&](int buf, int kt) {
    const int k0 = kt * 64;
    #pragma unroll
    for (int i = 0; i < 4; ++i) {
      const int Lb = (w * 4 + i) * 1024;
      const int L = Lb + lane * 16;
      const int row = L >> 7;           // 128B per LDS row (64 bf16)
      const int kcs = ((L >> 4) & 7) ^ (row & 7);  // pre-swizzled source chunk
      gll16(A  + (size_t)(m0 + row) * Kd + k0 + kcs * 8, (char*)As[buf] + Lb);
      gll16(Bt + (size_t)(n0 + row) * Kd + k0 + kcs * 8, (char*)Bs[buf] + Lb);
    }
  };

  f32x4 acc[4][4];
  #pragma unroll
  for (int i = 0; i < 4; ++i)
    #pragma unroll
    for (int j = 0; j < 4; ++j) acc[i][j] = f32x4{0.f, 0.f, 0.f, 0.f};

  const int wr = (w >> 1) * 64, wc = (w & 1) * 64;

  stage(0, 0);
  __syncthreads();
  for (int kt = 0; kt < 6; ++kt) {
    const int buf = kt & 1;
    if (kt + 1 < 6) stage(buf ^ 1, kt + 1);
    #pragma unroll
    for (int kk = 0; kk < 2; ++kk) {
      const int kc = kk * 4 + kh;
      short8 a[4], b[4];
      #pragma unroll
      for (int mi = 0; mi < 4; ++mi) {
        const int r = wr + mi * 16 + la;
        a[mi] = *(const short8*)((const char*)As[buf] + r * 128 + ((kc ^ (r & 7)) << 4));
      }
      #pragma unroll
      for (int ni = 0; ni < 4; ++ni) {
        const int r = wc + ni * 16 + la;
        b[ni] = *(const short8*)((const char*)Bs[buf] + r * 128 + ((kc ^ (r & 7)) << 4));
      }
      __builtin_amdgcn_s_setprio(1);
      #pragma unroll
      for (int mi = 0; mi < 4; ++mi)
        #pragma unroll
        for (int ni = 0; ni < 4; ++ni)
          acc[mi][ni] = __builtin_amdgcn_mfma_f32_16x16x32_bf16(a[mi], b[ni], acc[mi][ni], 0, 0, 0);
      __builtin_amdgcn_s_setprio(0);
    }
    __syncthreads();
  }

  if (MODE == 0) {
    const int qkv = n0 / 384;
    #pragma unroll
    for (int mi = 0; mi < 4; ++mi) {
      const int mbase = m0 + wr + mi * 16 + kh * 4;
      const int bb = mbase >> 8, tt = mbase & 255;
      #pragma unroll
      for (int ni = 0; ni < 4; ++ni) {
        const int nl = n0 + wc + ni * 16 + la;
        const int rel = nl - qkv * 384;
        const int hh = rel >> 6, dd = rel & 63;
        if (qkv == 0) {
          #pragma unroll
          for (int j = 0; j < 4; ++j)
            Qo[(((size_t)bb * 6 + hh) * 256 + (tt + j)) * 64 + dd] = f2bf(acc[mi][ni][j]);
        } else if (qkv == 1) {
          #pragma unroll
          for (int j = 0; j < 4; ++j)
            Ko[(((size_t)bb * 6 + hh) * 256 + (tt + j)) * 64 + dd] = f2bf(acc[mi][ni][j]);
        } else {
          u16x4 pk;
          #pragma unroll
          for (int j = 0; j < 4; ++j) pk[j] = f2bf(acc[mi][ni][j]);
          *(u16x4*)(Vto + (((size_t)bb * 6 + hh) * 64 + dd) * 256 + tt) = pk;  // Vt[b,h,d,t]
        }
      }
    }
  } else {
    #pragma unroll
    for (int mi = 0; mi < 4; ++mi) {
      const int mbase = m0 + wr + mi * 16 + kh * 4;
      #pragma unroll
      for (int ni = 0; ni < 4; ++ni) {
        const int nl = n0 + wc + ni * 16 + la;
        const float bn = bias[nl];
        #pragma unroll
        for (int j = 0; j < 4; ++j)
          Co[(size_t)(mbase + j) * 384 + nl] = acc[mi][ni][j] + bn;
      }
    }
  }
}

// ---------------- K2: attention, per-KEY (axis=2) softmax, 8 waves ----------------
// Wave w owns row-tiles {w, 15-w} (balanced causal work: 17 col-tiles each).
// Tile rt: rows [rt*16, rt*16+16), E strip cols [0, wp) with wp = 32*ceil((rt+1)/2).
__global__ __launch_bounds__(512, 1)
void attn_col(const unsigned short* __restrict__ Q, const unsigned short* __restrict__ K,
              const unsigned short* __restrict__ Vt, unsigned short* __restrict__ O)
{
  __shared__ __align__(16) char KL[32768];   // K [256][64] bf16, swizzled (8 chunks/row)
  __shared__ __align__(16) char VL[32768];   // V^T [64][256] bf16, swizzled (32 chunks/row)
  __shared__ __align__(16) char EL[73728];   // E strips, padded to K=32 multiples
  __shared__ float Lpart[8][256];
  __shared__ float invL[256];

  const int bh = blockIdx.x, tid = (int)threadIdx.x;
  const int w = tid >> 6, lane = tid & 63;
  const int la = lane & 15, kh = lane >> 4;
  const unsigned short* Qg = Q + (size_t)bh * 16384;
  const unsigned short* Kg = K + (size_t)bh * 16384;
  const unsigned short* Vg = Vt + (size_t)bh * 16384;

  // ---- stage K and V (async global->LDS), both at entry ----
  #pragma unroll
  for (int i = 0; i < 4; ++i) {
    const int Lb = i * 8192 + tid * 16;
    { const int row = Lb >> 7, kcs = ((Lb >> 4) & 7) ^ (row & 7);
      gll16(Kg + row * 64 + kcs * 8, KL + Lb); }
    { const int row = Lb >> 9, kcs = ((Lb >> 4) & 31) ^ (row & 7);
      gll16(Vg + row * 256 + kcs * 8, VL + Lb); }
  }
  __syncthreads();

  const int rts[2] = { w, 15 - w };
  int wps[2], eoffs[2];
  #pragma unroll
  for (int ti = 0; ti < 2; ++ti) {
    const int rt = rts[ti];
    wps[ti] = 32 * ((rt + 2) >> 1);
    const int S = (rt & 1) ? ((rt + 1) * (rt + 1) / 4) : (rt * (rt + 2) / 4);
    eoffs[ti] = 1024 * S;   // 32 bytes/row-col-unit: sum of previous strips
  }

  // ---- QK^T + masked exp -> E strips (bf16, swizzled mask 3) ----
  #pragma unroll
  for (int ti = 0; ti < 2; ++ti) {
    const int rt = rts[ti], wp = wps[ti], stride = wp * 2;
    char* Ebase = EL + eoffs[ti];
    short8 qa[2];
    #pragma unroll
    for (int kk = 0; kk < 2; ++kk)
      qa[kk] = *(const short8*)(Qg + (rt * 16 + la) * 64 + (kk * 4 + kh) * 8);
    const int nns = wp >> 4;
    for (int ns = 0; ns < nns; ++ns) {
      f32x4 s4 = f32x4{0.f, 0.f, 0.f, 0.f};
      #pragma unroll
      for (int kk = 0; kk < 2; ++kk) {
        const int rB = ns * 16 + la, kc = kk * 4 + kh;
        short8 bf = *(const short8*)(KL + rB * 128 + ((kc ^ (rB & 7)) << 4));
        s4 = __builtin_amdgcn_mfma_f32_16x16x32_bf16(qa[kk], bf, s4, 0, 0, 0);
      }
      const int c = ns * 16 + la, cc = c >> 3, co = (c & 7) * 2;
      #pragma unroll
      for (int j = 0; j < 4; ++j) {
        const int r = kh * 4 + j;
        const int t = rt * 16 + r;
        const float e = (t >= c) ? __expf(s4[j] * SCALE) : 0.f;
        *(unsigned short*)(Ebase + r * stride + ((cc ^ (r & 3)) << 4) + co) = f2bf(e);
      }
    }
  }
  __syncthreads();

  // ---- column partial sums over own strips (balanced) ----
  {
    float acc4[4] = {0.f, 0.f, 0.f, 0.f};
    #pragma unroll
    for (int ti = 0; ti < 2; ++ti) {
      const int wp = wps[ti], stride = wp * 2;
      const char* Ebase = EL + eoffs[ti];
      #pragma unroll
      for (int cb = 0; cb < 4; ++cb) {
        const int c = cb * 64 + lane;
        if (c < wp) {
          const int cc = c >> 3, co = (c & 7) * 2;
          float p = 0.f;
          #pragma unroll
          for (int r = 0; r < 16; ++r)
            p += bf2f(*(const unsigned short*)(Ebase + r * stride + ((cc ^ (r & 3)) << 4) + co));
          acc4[cb] += p;
        }
      }
    }
    #pragma unroll
    for (int cb = 0; cb < 4; ++cb) Lpart[w][cb * 64 + lane] = acc4[cb];
  }
  __syncthreads();
  if (tid < 256) {
    float Ls = 0.f;
    #pragma unroll
    for (int ww = 0; ww < 8; ++ww) Ls += Lpart[ww][tid];
    invL[tid] = 1.f / Ls;
  }
  __syncthreads();

  // ---- fold 1/L_s into V rows (VL physical chunks) ----
  {
    const int d = tid >> 3, qq = tid & 7;
    #pragma unroll
    for (int i = 0; i < 4; ++i) {
      const int kcp = qq * 4 + i;
      char* p = VL + d * 512 + kcp * 16;
      short8 v = *(short8*)p;
      const int sb = (kcp ^ (d & 7)) * 8;
      short8 o;
      #pragma unroll
      for (int e = 0; e < 8; ++e)
        o[e] = (short)f2bf(bf2f((unsigned short)v[e]) * invL[sb + e]);
      *(short8*)p = o;
    }
  }
  __syncthreads();

  // ---- O = E * V' ----
  const int b = bh / 6, h = bh - b * 6;
  unsigned short* Og = O + (size_t)b * 256 * 384 + h * 64;
  #pragma unroll
  for (int ti = 0; ti < 2; ++ti) {
    const int rt = rts[ti], wp = wps[ti], stride = wp * 2;
    const char* Ebase = EL + eoffs[ti];
    f32x4 oacc[4];
    #pragma unroll
    for (int nd = 0; nd < 4; ++nd) oacc[nd] = f32x4{0.f, 0.f, 0.f, 0.f};
    const int nks = wp >> 5;
    for (int ks = 0; ks < nks; ++ks) {
      const int cc = ks * 4 + kh;
      short8 ea = *(const short8*)(Ebase + la * stride + ((cc ^ (la & 3)) << 4));
      __builtin_amdgcn_s_setprio(1);
      #pragma unroll
      for (int nd = 0; nd < 4; ++nd) {
        const int d = nd * 16 + la;
        short8 vb = *(const short8*)(VL + d * 512 + ((cc ^ (d & 7)) << 4));
        oacc[nd] = __builtin_amdgcn_mfma_f32_16x16x32_bf16(ea, vb, oacc[nd], 0, 0, 0);
      }
      __builtin_amdgcn_s_setprio(0);
    }
    #pragma unroll
    for (int nd = 0; nd < 4; ++nd) {
      const int d = nd * 16 + la;
      #pragma unroll
      for (int j = 0; j < 4; ++j) {
        const int t = rt * 16 + kh * 4 + j;
        Og[(size_t)t * 384 + d] = f2bf(oacc[nd][j]);
      }
    }
  }
}

// ================= fallback (round-1 fp32 kernel) for small ws =================
__global__ __launch_bounds__(256, 1)
void mha_fused(const float* __restrict__ x, const float* __restrict__ Wq,
               const float* __restrict__ Wk, const float* __restrict__ Wv,
               const float* __restrict__ Wp, const float* __restrict__ bp,
               float* __restrict__ out)
{
  const int bh = blockIdx.x;
  const int b = bh / HEADS, h = bh % HEADS;
  const int tid = (int)threadIdx.x;
  const int wave = tid >> 6, lane = tid & 63;
  const float* xb = x + (size_t)b * TT * EMB;
  const float* wq = Wq + (size_t)h * EMB * DH;
  const float* wk = Wk + (size_t)h * EMB * DH;
  const float* wv = Wv + (size_t)h * EMB * DH;
  __shared__ float Ks[TT][68];
  __shared__ float Vs[TT][64];
  __shared__ float Qt[64][68];
  for (int c = 0; c < 4; ++c) {
    const int s0 = wave * 64 + c * 16;
    float ak[16], av[16];
    #pragma unroll
    for (int r = 0; r < 16; ++r) { ak[r] = 0.f; av[r] = 0.f; }
    for (int e = 0; e < EMB; ++e) {
      const float kk = wk[e * DH + lane];
      const float vv = wv[e * DH + lane];
      #pragma unroll
      for (int r = 0; r < 16; ++r) {
        const float xv = xb[(s0 + r) * EMB + e];
        ak[r] += xv * kk; av[r] += xv * vv;
      }
    }
    #pragma unroll
    for (int r = 0; r < 16; ++r) { Ks[s0 + r][lane] = ak[r]; Vs[s0 + r][lane] = av[r]; }
  }
  __syncthreads();
  const int s = tid;
  float kreg[64];
  {
    const float4* k4 = (const float4*)&Ks[s][0];
    #pragma unroll
    for (int i = 0; i < 16; ++i) {
      float4 kv = k4[i];
      kreg[4*i+0] = kv.x; kreg[4*i+1] = kv.y; kreg[4*i+2] = kv.z; kreg[4*i+3] = kv.w;
    }
  }
  float Lsum = 0.f;
  for (int tile = 0; tile < 4; ++tile) {
    {
      const int r0 = tile * 64 + wave * 16;
      float aq[16];
      #pragma unroll
      for (int r = 0; r < 16; ++r) aq[r] = 0.f;
      for (int e = 0; e < EMB; ++e) {
        const float qw = wq[e * DH + lane];
        #pragma unroll
        for (int r = 0; r < 16; ++r) aq[r] += xb[(r0 + r) * EMB + e] * qw;
      }
      __syncthreads();
      #pragma unroll
      for (int r = 0; r < 16; ++r) Qt[wave*16 + r][lane] = aq[r];
      __syncthreads();
    }
    const int tbase = tile * 64;
    if (tbase + 63 >= s) {
      for (int tr = 0; tr < 64; ++tr) {
        const int t = tbase + tr;
        if (t < s) continue;
        float w = 0.f;
        const float4* q4 = (const float4*)&Qt[tr][0];
        #pragma unroll
        for (int i = 0; i < 16; ++i) {
          float4 qv = q4[i];
          w += qv.x*kreg[4*i+0] + qv.y*kreg[4*i+1] + qv.z*kreg[4*i+2] + qv.w*kreg[4*i+3];
        }
        Lsum += __expf(w * SCALE);
      }
    }
  }
  __syncthreads();
  {
    const float invL = 1.0f / Lsum;
    float4* v4 = (float4*)&Vs[s][0];
    #pragma unroll
    for (int i = 0; i < 16; ++i) {
      float4 vv = v4[i];
      vv.x *= invL; vv.y *= invL; vv.z *= invL; vv.w *= invL;
      v4[i] = vv;
    }
  }
  __syncthreads();
  const float bias1 = bp[tid];
  const float bias2 = (tid < 128) ? bp[256 + tid] : 0.f;
  const int tr = tid >> 2, dq = tid & 3;
  float* ob = out + (size_t)b * TT * EMB;
  for (int tile = 0; tile < 4; ++tile) {
    {
      const int r0 = tile * 64 + wave * 16;
      float aq[16];
      #pragma unroll
      for (int r = 0; r < 16; ++r) aq[r] = 0.f;
      for (int e = 0; e < EMB; ++e) {
        const float qw = wq[e * DH + lane];
        #pragma unroll
        for (int r = 0; r < 16; ++r) aq[r] += xb[(r0 + r) * EMB + e] * qw;
      }
      __syncthreads();
      #pragma unroll
      for (int r = 0; r < 16; ++r) Qt[wave*16 + r][lane] = aq[r];
      __syncthreads();
    }
    const int t = tile * 64 + tr;
    float qreg[16];
    {
      const float4* q4 = (const float4*)&Qt[tr][dq * 16];
      #pragma unroll
      for (int i = 0; i < 4; ++i) {
        float4 qv = q4[i];
        qreg[4*i+0] = qv.x; qreg[4*i+1] = qv.y; qreg[4*i+2] = qv.z; qreg[4*i+3] = qv.w;
      }
    }
    float acc[16];
    #pragma unroll
    for (int i = 0; i < 16; ++i) acc[i] = 0.f;
    for (int s2 = 0; s2 <= t; ++s2) {
      const float4* kk4 = (const float4*)&Ks[s2][dq * 16];
      float part = 0.f;
      #pragma unroll
      for (int i = 0; i < 4; ++i) {
        float4 kv = kk4[i];
        part += qreg[4*i+0]*kv.x + qreg[4*i+1]*kv.y + qreg[4*i+2]*kv.z + qreg[4*i+3]*kv.w;
      }
      part += __shfl_xor(part, 1);
      part += __shfl_xor(part, 2);
      const float p = __expf(part * SCALE);
      const float4* vv4 = (const float4*)&Vs[s2][dq * 16];
      #pragma unroll
      for (int i = 0; i < 4; ++i) {
        float4 vv = vv4[i];
        acc[4*i+0] += p * vv.x; acc[4*i+1] += p * vv.y;
        acc[4*i+2] += p * vv.z; acc[4*i+3] += p * vv.w;
      }
    }
    __syncthreads();
    #pragma unroll
    for (int i = 0; i < 16; ++i) Qt[tr][dq*16 + i] = acc[i];
    __syncthreads();
    const int c1 = tid;
    const int c2 = 256 + tid;
    for (int rg = 0; rg < 4; ++rg) {
      float a1[16], a2[16];
      #pragma unroll
      for (int r = 0; r < 16; ++r) { a1[r] = 0.f; a2[r] = 0.f; }
      for (int d = 0; d < 64; ++d) {
        const float wp1 = Wp[(size_t)(h*64 + d) * EMB + c1];
        const float wp2 = (tid < 128) ? Wp[(size_t)(h*64 + d) * EMB + c2] : 0.f;
        #pragma unroll
        for (int r = 0; r < 16; ++r) {
          const float a = Qt[rg*16 + r][d];
          a1[r] += a * wp1; a2[r] += a * wp2;
        }
      }
      if (h == 0) {
        #pragma unroll
        for (int r = 0; r < 16; ++r) { a1[r] += bias1; a2[r] += bias2; }
      }
      const int trow0 = tile*64 + rg*16;
      #pragma unroll
      for (int r = 0; r < 16; ++r)
        atomicAdd(&ob[(size_t)(trow0 + r) * EMB + c1], a1[r]);
      if (tid < 128) {
        #pragma unroll
        for (int r = 0; r < 16; ++r)
          atomicAdd(&ob[(size_t)(trow0 + r) * EMB + c2], a2[r]);
      }
    }
    __syncthreads();
  }
}

extern "C" void kernel_launch(void* const* d_in, const int* in_sizes, int n_in,
                              void* d_out, int out_size, void* d_ws, size_t ws_size,
                              hipStream_t stream) {
  const float* x  = (const float*)d_in[0];
  const float* Wq = (const float*)d_in[1];
  const float* Wk = (const float*)d_in[2];
  const float* Wv = (const float*)d_in[3];
  const float* Wp = (const float*)d_in[4];
  const float* bp = (const float*)d_in[5];

  const int nb = in_sizes[0] / (TT * EMB);       // batch (128)
  const size_t M = (size_t)nb * TT;              // 32768 rows
  const size_t XB = M * EMB * 2;                 // bf16 activation bytes (25 MB)

  const size_t off_x  = 0;
  const size_t off_wt = XB;
  const size_t off_q  = off_wt + (size_t)1536 * 384 * 2;
  const size_t off_k  = off_q + XB;
  const size_t off_vt = off_k + XB;
  const size_t off_o  = 0;                       // O overlays xb16 (stream-ordered safe)
  const size_t need   = off_vt + XB;

  if (ws_size < need) {
    hipMemsetAsync(d_out, 0, (size_t)out_size * sizeof(float), stream);
    mha_fused<<<nb * HEADS, 256, 0, stream>>>(x, Wq, Wk, Wv, Wp, bp, (float*)d_out);
    return;
  }

  char* ws = (char*)d_ws;
  unsigned short* xb16 = (unsigned short*)(ws + off_x);
  unsigned short* Wt   = (unsigned short*)(ws + off_wt);
  unsigned short* Qw   = (unsigned short*)(ws + off_q);
  unsigned short* Kw   = (unsigned short*)(ws + off_k);
  unsigned short* Vtw  = (unsigned short*)(ws + off_vt);
  unsigned short* Ow   = (unsigned short*)(ws + off_o);

  const int n8 = (int)(M * EMB / 8);
  cvt_x<<<(n8 + 255) / 256, 256, 0, stream>>>(x, xb16, n8);
  build_wt<<<288, 256, 0, stream>>>(Wq, Wk, Wv, Wp, Wt);

  dim3 g1(9, (unsigned)(M / 128));
  gemm_bt<0><<<g1, 256, 0, stream>>>(xb16, Wt, Qw, Kw, Vtw, nullptr, nullptr);

  attn_col<<<nb * HEADS, 512, 0, stream>>>(Qw, Kw, Vtw, Ow);

  dim3 g3(3, (unsigned)(M / 128));
  gemm_bt<1><<<g3, 256, 0, stream>>>(Ow, Wt + (size_t)1152 * 384, nullptr, nullptr, nullptr,
                                     (float*)d_out, bp);
}

// Round 4
// 126.961 us; speedup vs baseline: 35.5541x; 1.1145x over previous
//
#include <hip/hip_runtime.h>

#define EMB 384
#define HEADS 6
#define DH 64
#define TT 256

constexpr float SCALE = 0.05103103630798288f;  // 384^-0.5

typedef __attribute__((ext_vector_type(8))) short short8;
typedef __attribute__((ext_vector_type(4))) float f32x4;
typedef __attribute__((ext_vector_type(4))) unsigned short u16x4;

__device__ __forceinline__ unsigned short f2bf(float f) {
  unsigned int u = __builtin_bit_cast(unsigned int, f);
  u += 0x7FFFu + ((u >> 16) & 1u);   // RNE
  return (unsigned short)(u >> 16);
}
__device__ __forceinline__ float bf2f(unsigned short u) {
  unsigned int v = ((unsigned int)u) << 16;
  return __builtin_bit_cast(float, v);
}
__device__ __forceinline__ void gll16(const void* g, void* l) {
  __builtin_amdgcn_global_load_lds(
      (const __attribute__((address_space(1))) unsigned int*)g,
      (__attribute__((address_space(3))) unsigned int*)l, 16, 0, 0);
}

// ---------------- K0: build Wt[1536][384] bf16 (rows: q 0-383 | k | v | proj^T) ----
__global__ __launch_bounds__(256)
void build_wt(const float* __restrict__ Wq, const float* __restrict__ Wk,
              const float* __restrict__ Wv, const float* __restrict__ Wp,
              unsigned short* __restrict__ Wt) {
  int idx = blockIdx.x * 256 + threadIdx.x;  // 1536*48 = 73728
  int n = idx / 48, e0 = (idx % 48) * 8;
  const float* src; int stride;
  if (n < 1152) {
    int qkv = n / 384, rel = n % 384, h = rel >> 6, d = rel & 63;
    const float* W = (qkv == 0) ? Wq : (qkv == 1) ? Wk : Wv;
    src = W + ((size_t)h * EMB + e0) * DH + d; stride = DH;
  } else {
    int c = n - 1152;
    src = Wp + (size_t)e0 * EMB + c; stride = EMB;
  }
  short8 o;
  #pragma unroll
  for (int j = 0; j < 8; ++j) o[j] = (short)f2bf(src[j * stride]);
  ((short8*)Wt)[idx] = o;
}

// ---------------- panel-persistent GEMM ----------------
// Each block owns a 128-row A-panel (staged to LDS ONCE, full K=384),
// loops over all N-tiles with 16KB B-chunks double-buffered.
// MODE 0: A = x (fp32, converted in-stage), NT=9, QKV epilogue (bf16, V transposed).
// MODE 1: A = O (bf16), NT=3, proj epilogue (fp32 + bias).
template<int MODE>
__global__ __launch_bounds__(512, 1)
void gemm_panel(const void* __restrict__ Asrc, const unsigned short* __restrict__ Bt,
                unsigned short* __restrict__ Qo, unsigned short* __restrict__ Ko,
                unsigned short* __restrict__ Vto,
                float* __restrict__ Co, const float* __restrict__ bias)
{
  constexpr int NT = (MODE == 0) ? 9 : 3;
  __shared__ __align__(16) unsigned short AL[128 * 384];    // 98304 B, rows of 768B
  __shared__ __align__(16) unsigned short BL[2][128 * 64];  // 2 x 16384 B
  const int tid = (int)threadIdx.x, w = tid >> 6, lane = tid & 63;
  const int la = lane & 15, kh = lane >> 4;
  const int m0 = blockIdx.x * 128;

  // ---- stage A panel once (reg-convert + swizzled ds_write) ----
  {
    const int row = tid >> 2, qq = tid & 3;
    if (MODE == 0) {
      const float4* x4 = (const float4*)((const float*)Asrc + (size_t)(m0 + row) * 384);
      #pragma unroll
      for (int i = 0; i < 12; ++i) {
        const int ch = qq + 4 * i;
        float4 va = x4[ch * 2], vb = x4[ch * 2 + 1];
        short8 o;
        o[0] = (short)f2bf(va.x); o[1] = (short)f2bf(va.y);
        o[2] = (short)f2bf(va.z); o[3] = (short)f2bf(va.w);
        o[4] = (short)f2bf(vb.x); o[5] = (short)f2bf(vb.y);
        o[6] = (short)f2bf(vb.z); o[7] = (short)f2bf(vb.w);
        *(short8*)((char*)AL + row * 768 + ((ch ^ (row & 7)) << 4)) = o;
      }
    } else {
      const short8* O8 = (const short8*)((const unsigned short*)Asrc + (size_t)(m0 + row) * 384);
      #pragma unroll
      for (int i = 0; i < 12; ++i) {
        const int ch = qq + 4 * i;
        *(short8*)((char*)AL + row * 768 + ((ch ^ (row & 7)) << 4)) = O8[ch];
      }
    }
  }

  auto stageB = [&](int buf, int n0, int k0) {
    #pragma unroll
    for (int i = 0; i < 2; ++i) {
      const int Lb = i * 8192 + tid * 16;
      const int row = Lb >> 7;
      const int kcs = ((Lb >> 4) & 7) ^ (row & 7);
      gll16(Bt + (size_t)(n0 + row) * 384 + k0 + kcs * 8, (char*)BL[buf] + Lb);
    }
  };

  stageB(0, 0, 0);
  __syncthreads();   // drains A ds_writes (lgkm) + B gll (vmcnt)

  const int wr = (w >> 2) * 64, wc = (w & 3) * 32;
  int buf = 0;
  for (int nt = 0; nt < NT; ++nt) {
    f32x4 acc[4][2];
    #pragma unroll
    for (int i = 0; i < 4; ++i)
      #pragma unroll
      for (int j = 0; j < 2; ++j) acc[i][j] = f32x4{0.f, 0.f, 0.f, 0.f};

    for (int kt = 0; kt < 6; ++kt) {
      if (kt < 5)            stageB(buf ^ 1, nt * 128, (kt + 1) * 64);
      else if (nt + 1 < NT)  stageB(buf ^ 1, (nt + 1) * 128, 0);
      #pragma unroll
      for (int kk = 0; kk < 2; ++kk) {
        short8 a[4], b[2];
        const int chA = kt * 8 + kk * 4 + kh;
        #pragma unroll
        for (int mi = 0; mi < 4; ++mi) {
          const int r = wr + mi * 16 + la;
          a[mi] = *(const short8*)((const char*)AL + r * 768 + ((chA ^ (r & 7)) << 4));
        }
        const int chB = kk * 4 + kh;
        #pragma unroll
        for (int ni = 0; ni < 2; ++ni) {
          const int rB = wc + ni * 16 + la;
          b[ni] = *(const short8*)((const char*)BL[buf] + rB * 128 + ((chB ^ (rB & 7)) << 4));
        }
        __builtin_amdgcn_s_setprio(1);
        #pragma unroll
        for (int mi = 0; mi < 4; ++mi)
          #pragma unroll
          for (int ni = 0; ni < 2; ++ni)
            acc[mi][ni] = __builtin_amdgcn_mfma_f32_16x16x32_bf16(a[mi], b[ni], acc[mi][ni], 0, 0, 0);
        __builtin_amdgcn_s_setprio(0);
      }
      __syncthreads();
      buf ^= 1;
    }

    // ---- epilogue for this N-tile ----
    if (MODE == 0) {
      const int qkv = nt / 3;                   // tiles 0-2:q, 3-5:k, 6-8:v
      #pragma unroll
      for (int mi = 0; mi < 4; ++mi) {
        const int mbase = m0 + wr + mi * 16 + kh * 4;
        const int bb = mbase >> 8, tt = mbase & 255;
        #pragma unroll
        for (int ni = 0; ni < 2; ++ni) {
          const int nl = nt * 128 + wc + ni * 16 + la;
          const int rel = nl - qkv * 384;
          const int hh = rel >> 6, dd = rel & 63;
          if (qkv == 0) {
            #pragma unroll
            for (int j = 0; j < 4; ++j)
              Qo[(((size_t)bb * 6 + hh) * 256 + (tt + j)) * 64 + dd] = f2bf(acc[mi][ni][j]);
          } else if (qkv == 1) {
            #pragma unroll
            for (int j = 0; j < 4; ++j)
              Ko[(((size_t)bb * 6 + hh) * 256 + (tt + j)) * 64 + dd] = f2bf(acc[mi][ni][j]);
          } else {
            u16x4 pk;
            #pragma unroll
            for (int j = 0; j < 4; ++j) pk[j] = f2bf(acc[mi][ni][j]);
            *(u16x4*)(Vto + (((size_t)bb * 6 + hh) * 64 + dd) * 256 + tt) = pk;  // Vt[b,h,d,t]
          }
        }
      }
    } else {
      #pragma unroll
      for (int mi = 0; mi < 4; ++mi) {
        const int mbase = m0 + wr + mi * 16 + kh * 4;
        #pragma unroll
        for (int ni = 0; ni < 2; ++ni) {
          const int nl = nt * 128 + wc + ni * 16 + la;
          const float bn = bias[nl];
          #pragma unroll
          for (int j = 0; j < 4; ++j)
            Co[(size_t)(mbase + j) * 384 + nl] = acc[mi][ni][j] + bn;
        }
      }
    }
  }
}

// ---------------- K2: attention, per-KEY (axis=2) softmax, 8 waves ----------------
__global__ __launch_bounds__(512, 1)
void attn_col(const unsigned short* __restrict__ Q, const unsigned short* __restrict__ K,
              const unsigned short* __restrict__ Vt, unsigned short* __restrict__ O)
{
  __shared__ __align__(16) char KL[32768];   // K [256][64] bf16, swizzled (8 chunks/row)
  __shared__ __align__(16) char VL[32768];   // V^T [64][256] bf16, swizzled (32 chunks/row)
  __shared__ __align__(16) char EL[73728];   // E strips, padded to K=32 multiples
  __shared__ float Lpart[8][256];
  __shared__ float invL[256];

  const int bh = blockIdx.x, tid = (int)threadIdx.x;
  const int w = tid >> 6, lane = tid & 63;
  const int la = lane & 15, kh = lane >> 4;
  const unsigned short* Qg = Q + (size_t)bh * 16384;
  const unsigned short* Kg = K + (size_t)bh * 16384;
  const unsigned short* Vg = Vt + (size_t)bh * 16384;

  #pragma unroll
  for (int i = 0; i < 4; ++i) {
    const int Lb = i * 8192 + tid * 16;
    { const int row = Lb >> 7, kcs = ((Lb >> 4) & 7) ^ (row & 7);
      gll16(Kg + row * 64 + kcs * 8, KL + Lb); }
    { const int row = Lb >> 9, kcs = ((Lb >> 4) & 31) ^ (row & 7);
      gll16(Vg + row * 256 + kcs * 8, VL + Lb); }
  }
  __syncthreads();

  const int rts[2] = { w, 15 - w };
  int wps[2], eoffs[2];
  #pragma unroll
  for (int ti = 0; ti < 2; ++ti) {
    const int rt = rts[ti];
    wps[ti] = 32 * ((rt + 2) >> 1);
    const int S = (rt & 1) ? ((rt + 1) * (rt + 1) / 4) : (rt * (rt + 2) / 4);
    eoffs[ti] = 1024 * S;
  }

  // ---- QK^T + masked exp -> E strips ----
  #pragma unroll
  for (int ti = 0; ti < 2; ++ti) {
    const int rt = rts[ti], wp = wps[ti], stride = wp * 2;
    char* Ebase = EL + eoffs[ti];
    short8 qa[2];
    #pragma unroll
    for (int kk = 0; kk < 2; ++kk)
      qa[kk] = *(const short8*)(Qg + (rt * 16 + la) * 64 + (kk * 4 + kh) * 8);
    const int nns = wp >> 4;
    for (int ns = 0; ns < nns; ++ns) {
      f32x4 s4 = f32x4{0.f, 0.f, 0.f, 0.f};
      #pragma unroll
      for (int kk = 0; kk < 2; ++kk) {
        const int rB = ns * 16 + la, kc = kk * 4 + kh;
        short8 bf = *(const short8*)(KL + rB * 128 + ((kc ^ (rB & 7)) << 4));
        s4 = __builtin_amdgcn_mfma_f32_16x16x32_bf16(qa[kk], bf, s4, 0, 0, 0);
      }
      const int c = ns * 16 + la, cc = c >> 3, co = (c & 7) * 2;
      #pragma unroll
      for (int j = 0; j < 4; ++j) {
        const int r = kh * 4 + j;
        const int t = rt * 16 + r;
        const float e = (t >= c) ? __expf(s4[j] * SCALE) : 0.f;
        *(unsigned short*)(Ebase + r * stride + ((cc ^ (r & 3)) << 4) + co) = f2bf(e);
      }
    }
  }
  __syncthreads();

  // ---- column partial sums ----
  {
    float acc4[4] = {0.f, 0.f, 0.f, 0.f};
    #pragma unroll
    for (int ti = 0; ti < 2; ++ti) {
      const int wp = wps[ti], stride = wp * 2;
      const char* Ebase = EL + eoffs[ti];
      #pragma unroll
      for (int cb = 0; cb < 4; ++cb) {
        const int c = cb * 64 + lane;
        if (c < wp) {
          const int cc = c >> 3, co = (c & 7) * 2;
          float p = 0.f;
          #pragma unroll
          for (int r = 0; r < 16; ++r)
            p += bf2f(*(const unsigned short*)(Ebase + r * stride + ((cc ^ (r & 3)) << 4) + co));
          acc4[cb] += p;
        }
      }
    }
    #pragma unroll
    for (int cb = 0; cb < 4; ++cb) Lpart[w][cb * 64 + lane] = acc4[cb];
  }
  __syncthreads();
  if (tid < 256) {
    float Ls = 0.f;
    #pragma unroll
    for (int ww = 0; ww < 8; ++ww) Ls += Lpart[ww][tid];
    invL[tid] = 1.f / Ls;
  }
  __syncthreads();

  // ---- fold 1/L_s into V ----
  {
    const int d = tid >> 3, qq = tid & 7;
    #pragma unroll
    for (int i = 0; i < 4; ++i) {
      const int kcp = qq * 4 + i;
      char* p = VL + d * 512 + kcp * 16;
      short8 v = *(short8*)p;
      const int sb = (kcp ^ (d & 7)) * 8;
      short8 o;
      #pragma unroll
      for (int e = 0; e < 8; ++e)
        o[e] = (short)f2bf(bf2f((unsigned short)v[e]) * invL[sb + e]);
      *(short8*)p = o;
    }
  }
  __syncthreads();

  // ---- O = E * V' ----
  const int b = bh / 6, h = bh - b * 6;
  unsigned short* Og = O + (size_t)b * 256 * 384 + h * 64;
  #pragma unroll
  for (int ti = 0; ti < 2; ++ti) {
    const int rt = rts[ti], wp = wps[ti], stride = wp * 2;
    const char* Ebase = EL + eoffs[ti];
    f32x4 oacc[4];
    #pragma unroll
    for (int nd = 0; nd < 4; ++nd) oacc[nd] = f32x4{0.f, 0.f, 0.f, 0.f};
    const int nks = wp >> 5;
    for (int ks = 0; ks < nks; ++ks) {
      const int cc = ks * 4 + kh;
      short8 ea = *(const short8*)(Ebase + la * stride + ((cc ^ (la & 3)) << 4));
      __builtin_amdgcn_s_setprio(1);
      #pragma unroll
      for (int nd = 0; nd < 4; ++nd) {
        const int d = nd * 16 + la;
        short8 vb = *(const short8*)(VL + d * 512 + ((cc ^ (d & 7)) << 4));
        oacc[nd] = __builtin_amdgcn_mfma_f32_16x16x32_bf16(ea, vb, oacc[nd], 0, 0, 0);
      }
      __builtin_amdgcn_s_setprio(0);
    }
    #pragma unroll
    for (int nd = 0; nd < 4; ++nd) {
      const int d = nd * 16 + la;
      #pragma unroll
      for (int j = 0; j < 4; ++j) {
        const int t = rt * 16 + kh * 4 + j;
        Og[(size_t)t * 384 + d] = f2bf(oacc[nd][j]);
      }
    }
  }
}

// ================= fallback (fp32) for small ws =================
__global__ __launch_bounds__(256, 1)
void mha_fused(const float* __restrict__ x, const float* __restrict__ Wq,
               const float* __restrict__ Wk, const float* __restrict__ Wv,
               const float* __restrict__ Wp, const float* __restrict__ bp,
               float* __restrict__ out)
{
  const int bh = blockIdx.x;
  const int b = bh / HEADS, h = bh % HEADS;
  const int tid = (int)threadIdx.x;
  const int wave = tid >> 6, lane = tid & 63;
  const float* xb = x + (size_t)b * TT * EMB;
  const float* wq = Wq + (size_t)h * EMB * DH;
  const float* wk = Wk + (size_t)h * EMB * DH;
  const float* wv = Wv + (size_t)h * EMB * DH;
  __shared__ float Ks[TT][68];
  __shared__ float Vs[TT][64];
  __shared__ float Qt[64][68];
  for (int c = 0; c < 4; ++c) {
    const int s0 = wave * 64 + c * 16;
    float ak[16], av[16];
    #pragma unroll
    for (int r = 0; r < 16; ++r) { ak[r] = 0.f; av[r] = 0.f; }
    for (int e = 0; e < EMB; ++e) {
      const float kk = wk[e * DH + lane];
      const float vv = wv[e * DH + lane];
      #pragma unroll
      for (int r = 0; r < 16; ++r) {
        const float xv = xb[(s0 + r) * EMB + e];
        ak[r] += xv * kk; av[r] += xv * vv;
      }
    }
    #pragma unroll
    for (int r = 0; r < 16; ++r) { Ks[s0 + r][lane] = ak[r]; Vs[s0 + r][lane] = av[r]; }
  }
  __syncthreads();
  const int s = tid;
  float kreg[64];
  {
    const float4* k4 = (const float4*)&Ks[s][0];
    #pragma unroll
    for (int i = 0; i < 16; ++i) {
      float4 kv = k4[i];
      kreg[4*i+0] = kv.x; kreg[4*i+1] = kv.y; kreg[4*i+2] = kv.z; kreg[4*i+3] = kv.w;
    }
  }
  float Lsum = 0.f;
  for (int tile = 0; tile < 4; ++tile) {
    {
      const int r0 = tile * 64 + wave * 16;
      float aq[16];
      #pragma unroll
      for (int r = 0; r < 16; ++r) aq[r] = 0.f;
      for (int e = 0; e < EMB; ++e) {
        const float qw = wq[e * DH + lane];
        #pragma unroll
        for (int r = 0; r < 16; ++r) aq[r] += xb[(r0 + r) * EMB + e] * qw;
      }
      __syncthreads();
      #pragma unroll
      for (int r = 0; r < 16; ++r) Qt[wave*16 + r][lane] = aq[r];
      __syncthreads();
    }
    const int tbase = tile * 64;
    if (tbase + 63 >= s) {
      for (int tr = 0; tr < 64; ++tr) {
        const int t = tbase + tr;
        if (t < s) continue;
        float w = 0.f;
        const float4* q4 = (const float4*)&Qt[tr][0];
        #pragma unroll
        for (int i = 0; i < 16; ++i) {
          float4 qv = q4[i];
          w += qv.x*kreg[4*i+0] + qv.y*kreg[4*i+1] + qv.z*kreg[4*i+2] + qv.w*kreg[4*i+3];
        }
        Lsum += __expf(w * SCALE);
      }
    }
  }
  __syncthreads();
  {
    const float invL = 1.0f / Lsum;
    float4* v4 = (float4*)&Vs[s][0];
    #pragma unroll
    for (int i = 0; i < 16; ++i) {
      float4 vv = v4[i];
      vv.x *= invL; vv.y *= invL; vv.z *= invL; vv.w *= invL;
      v4[i] = vv;
    }
  }
  __syncthreads();
  const float bias1 = bp[tid];
  const float bias2 = (tid < 128) ? bp[256 + tid] : 0.f;
  const int tr = tid >> 2, dq = tid & 3;
  float* ob = out + (size_t)b * TT * EMB;
  for (int tile = 0; tile < 4; ++tile) {
    {
      const int r0 = tile * 64 + wave * 16;
      float aq[16];
      #pragma unroll
      for (int r = 0; r < 16; ++r) aq[r] = 0.f;
      for (int e = 0; e < EMB; ++e) {
        const float qw = wq[e * DH + lane];
        #pragma unroll
        for (int r = 0; r < 16; ++r) aq[r] += xb[(r0 + r) * EMB + e] * qw;
      }
      __syncthreads();
      #pragma unroll
      for (int r = 0; r < 16; ++r) Qt[wave*16 + r][lane] = aq[r];
      __syncthreads();
    }
    const int t = tile * 64 + tr;
    float qreg[16];
    {
      const float4* q4 = (const float4*)&Qt[tr][dq * 16];
      #pragma unroll
      for (int i = 0; i < 4; ++i) {
        float4 qv = q4[i];
        qreg[4*i+0] = qv.x; qreg[4*i+1] = qv.y; qreg[4*i+2] = qv.z; qreg[4*i+3] = qv.w;
      }
    }
    float acc[16];
    #pragma unroll
    for (int i = 0; i < 16; ++i) acc[i] = 0.f;
    for (int s2 = 0; s2 <= t; ++s2) {
      const float4* kk4 = (const float4*)&Ks[s2][dq * 16];
      float part = 0.f;
      #pragma unroll
      for (int i = 0; i < 4; ++i) {
        float4 kv = kk4[i];
        part += qreg[4*i+0]*kv.x + qreg[4*i+1]*kv.y + qreg[4*i+2]*kv.z + qreg[4*i+3]*kv.w;
      }
      part += __shfl_xor(part, 1);
      part += __shfl_xor(part, 2);
      const float p = __expf(part * SCALE);
      const float4* vv4 = (const float4*)&Vs[s2][dq * 16];
      #pragma unroll
      for (int i = 0; i < 4; ++i) {
        float4 vv = vv4[i];
        acc[4*i+0] += p * vv.x; acc[4*i+1] += p * vv.y;
        acc[4*i+2] += p * vv.z; acc[4*i+3] += p * vv.w;
      }
    }
    __syncthreads();
    #pragma unroll
    for (int i = 0; i < 16; ++i) Qt[tr][dq*16 + i] = acc[i];
    __syncthreads();
    const int c1 = tid;
    const int c2 = 256 + tid;
    for (int rg = 0; rg < 4; ++rg) {
      float a1[16], a2[16];
      #pragma unroll
      for (int r = 0; r < 16; ++r) { a1[r] = 0.f; a2[r] = 0.f; }
      for (int d = 0; d < 64; ++d) {
        const float wp1 = Wp[(size_t)(h*64 + d) * EMB + c1];
        const float wp2 = (tid < 128) ? Wp[(size_t)(h*64 + d) * EMB + c2] : 0.f;
        #pragma unroll
        for (int r = 0; r < 16; ++r) {
          const float a = Qt[rg*16 + r][d];
          a1[r] += a * wp1; a2[r] += a * wp2;
        }
      }
      if (h == 0) {
        #pragma unroll
        for (int r = 0; r < 16; ++r) { a1[r] += bias1; a2[r] += bias2; }
      }
      const int trow0 = tile*64 + rg*16;
      #pragma unroll
      for (int r = 0; r < 16; ++r)
        atomicAdd(&ob[(size_t)(trow0 + r) * EMB + c1], a1[r]);
      if (tid < 128) {
        #pragma unroll
        for (int r = 0; r < 16; ++r)
          atomicAdd(&ob[(size_t)(trow0 + r) * EMB + c2], a2[r]);
      }
    }
    __syncthreads();
  }
}

extern "C" void kernel_launch(void* const* d_in, const int* in_sizes, int n_in,
                              void* d_out, int out_size, void* d_ws, size_t ws_size,
                              hipStream_t stream) {
  const float* x  = (const float*)d_in[0];
  const float* Wq = (const float*)d_in[1];
  const float* Wk = (const float*)d_in[2];
  const float* Wv = (const float*)d_in[3];
  const float* Wp = (const float*)d_in[4];
  const float* bp = (const float*)d_in[5];

  const int nb = in_sizes[0] / (TT * EMB);       // batch (128)
  const size_t M = (size_t)nb * TT;              // 32768 rows
  const size_t XB = M * EMB * 2;                 // bf16 activation bytes (25 MB)
  const size_t WT = (size_t)1536 * 384 * 2;

  const size_t off_wt = 0;
  const size_t off_q  = off_wt + WT;
  const size_t off_k  = off_q + XB;
  const size_t off_vt = off_k + XB;
  const size_t off_o  = off_vt + XB;
  const size_t need   = off_o + XB;

  if (ws_size < need) {
    hipMemsetAsync(d_out, 0, (size_t)out_size * sizeof(float), stream);
    mha_fused<<<nb * HEADS, 256, 0, stream>>>(x, Wq, Wk, Wv, Wp, bp, (float*)d_out);
    return;
  }

  char* ws = (char*)d_ws;
  unsigned short* Wt  = (unsigned short*)(ws + off_wt);
  unsigned short* Qw  = (unsigned short*)(ws + off_q);
  unsigned short* Kw  = (unsigned short*)(ws + off_k);
  unsigned short* Vtw = (unsigned short*)(ws + off_vt);
  unsigned short* Ow  = (unsigned short*)(ws + off_o);

  build_wt<<<288, 256, 0, stream>>>(Wq, Wk, Wv, Wp, Wt);

  gemm_panel<0><<<(unsigned)(M / 128), 512, 0, stream>>>(
      (const void*)x, Wt, Qw, Kw, Vtw, nullptr, nullptr);

  attn_col<<<nb * HEADS, 512, 0, stream>>>(Qw, Kw, Vtw, Ow);

  gemm_panel<1><<<(unsigned)(M / 128), 512, 0, stream>>>(
      (const void*)Ow, Wt + (size_t)1152 * 384, nullptr, nullptr, nullptr,
      (float*)d_out, bp);
}